// Round 1
// baseline (1857.531 us; speedup 1.0000x reference)
//
#include <hip/hip_runtime.h>

#define N_NODES 20000
#define N_EDGES 320000
#define E_TOT   340000   // edges + self loops
#define N_GRAPHS 64
#define N_CLASSES 5
#define SLOPE 0.2f
#define EPS_BN 1e-5f

// persistent megakernel geometry: 768 blocks x 256 thr = 3 blocks/CU on 256 CUs.
// co-residency guaranteed by __launch_bounds__(256,3): VGPR<=170, LDS 17.5KB<=53KB/CU.
#define NB 768
#define CB 96            // CSR-builder blocks inside phase 1
#define NCH 209          // ceil(N_NODES / CB)

typedef _Float16 v8h __attribute__((ext_vector_type(8)));  // 8 fp16 (4 VGPRs) MFMA operand
typedef float v4f __attribute__((ext_vector_type(4)));     // 4 f32 acc
typedef _Float16 v4h __attribute__((ext_vector_type(4)));  // 4 fp16 (8 B)

#define SPQ (N_NODES * 512 / 4)
#define W1E (512 * 256)
#define W2E (256 * 256)
#define W3E (256 * 64)
#define ALZ (80000 * 4 + 20000 * 2)   // als1,ald1,als2,ald2 (4x80000) + als3,ald3 (2x20000)
#define PREP_IDS (SPQ + W1E + W2E + W3E + N_NODES + N_NODES + N_GRAPHS * 64 + ALZ)

// ctrl[] slot map (all zeroed by hipMemsetAsync before launch; one-shot per replay):
//  0,2,4,6,8,10,12 : 7 grid-sync pairs {count, release}
//  14,16,18        : 3 CSR mini-barrier pairs (CB blocks)
//  20,21,22        : work-stealing tile cursors for GEMM1/2/3
#define GS0 0
#define GS1 2
#define GS2 4
#define GS3 6
#define GS4 8
#define GS5 10
#define GS6 12
#define MB0 14
#define MB1 16
#define MB2 18
#define CUR1 20
#define CUR2 21
#define CUR3 22

struct MegaArgs {
    const float* x; const int* ei; const int* batch;
    const float* W1; const float* a1s; const float* a1d; const float* b1;
    const float* g1; const float* be1; const float* mu1; const float* va1;
    const float* W2; const float* a2s; const float* a2d; const float* b2;
    const float* g2; const float* be2; const float* mu2; const float* va2;
    const float* W3; const float* a3s; const float* a3d; const float* b3;
    const float* l1w; const float* l1b; const float* l2w; const float* l2b;
    float* out;
    _Float16* xh; _Float16* bufH; _Float16* bufH3;
    _Float16* bt1; _Float16* bt2; _Float16* bt3;
    float* als1; float* ald1; float* als2; float* ald2; float* als3; float* ald3;
    float* albase;
    int* cnt; int* wptr; int* indptr; int* esrc; int* gstart;
    float* sums; int* blocksum; int* ctrl;
};

// ---- device-scope barrier over `nb` blocks; slot = {count, release}, pre-zeroed ----
__device__ __forceinline__ void gbar(int* slot, int nb) {
    __syncthreads();
    if (threadIdx.x == 0) {
        __threadfence();   // publish this block's writes device-wide (agent-scope fence)
        if (__hip_atomic_fetch_add(slot, 1, __ATOMIC_ACQ_REL, __HIP_MEMORY_SCOPE_AGENT) == nb - 1) {
            __hip_atomic_store(slot + 1, 1, __ATOMIC_RELEASE, __HIP_MEMORY_SCOPE_AGENT);
        } else {
            while (!__hip_atomic_load(slot + 1, __ATOMIC_ACQUIRE, __HIP_MEMORY_SCOPE_AGENT))
                __builtin_amdgcn_s_sleep(1);
        }
        __threadfence();   // invalidate stale cached lines before post-barrier reads
    }
    __syncthreads();
}

// ---- grid-stride prep work item (identical math to verified k_prep) ----
__device__ __forceinline__ void prep_one(int id, const MegaArgs& a) {
    if (id < SPQ) {
        const float4 v = *(const float4*)(a.x + (size_t)id * 4);
        v4h h;
        h.x = (_Float16)v.x; h.y = (_Float16)v.y; h.z = (_Float16)v.z; h.w = (_Float16)v.w;
        *(v4h*)(a.xh + (size_t)id * 4) = h;
        return;
    }
    id -= SPQ;
    if (id < W1E) {
        const int K = 512, N = 256;
        int n = id / K, k = id - n * K;
        a.bt1[id] = (_Float16)a.W1[(size_t)k * N + n];
        return;
    }
    id -= W1E;
    if (id < W2E) {
        const int K = 256, N = 256;
        int n = id / K, k = id - n * K;
        a.bt2[id] = (_Float16)a.W2[(size_t)k * N + n];
        return;
    }
    id -= W2E;
    if (id < W3E) {
        const int K = 256, N = 64;
        int n = id / K, k = id - n * K;
        a.bt3[id] = (_Float16)a.W3[(size_t)k * N + n];
        return;
    }
    id -= W3E;
    if (id < N_NODES) {
        int i = id;
        int b = a.batch[i];
        if (i == 0) {
            for (int g = 0; g <= b; ++g) a.gstart[g] = 0;
        } else {
            int p = a.batch[i - 1];
            for (int g = p + 1; g <= b; ++g) a.gstart[g] = i;
        }
        if (i == N_NODES - 1) {
            for (int g = b + 1; g <= N_GRAPHS; ++g) a.gstart[g] = N_NODES;
        }
        return;
    }
    id -= N_NODES;
    if (id < N_NODES) { a.cnt[id] = 0; return; }
    id -= N_NODES;
    if (id < N_GRAPHS * 64) { a.sums[id] = 0.f; return; }
    id -= N_GRAPHS * 64;
    if (id < ALZ) a.albase[id] = 0.f;
}

// ---- CSR build on CB blocks (count -> two-level scan -> scatter), self-synced ----
__device__ void csr_build(const MegaArgs& a, int bid, int tid, int* ssc) {
    // count
    for (int e = bid * 256 + tid; e < E_TOT; e += CB * 256) {
        int d = (e < N_EDGES) ? a.ei[N_EDGES + e] : (e - N_EDGES);
        atomicAdd(&a.cnt[d], 1);
    }
    gbar(a.ctrl + MB0, CB);
    // scan stage 1: block-local scan over NCH contiguous nodes (1 node / thread)
    const int i = bid * NCH + tid;
    const int active = (tid < NCH && i < N_NODES);
    int ls = active ? a.cnt[i] : 0;
    ssc[tid] = ls;
    __syncthreads();
    for (int off = 1; off < 256; off <<= 1) {
        int v = (tid >= off) ? ssc[tid - off] : 0;
        __syncthreads();
        ssc[tid] += v;
        __syncthreads();
    }
    const int epre = ssc[tid] - ls;       // exclusive prefix within block chunk
    if (tid == 255) a.blocksum[bid] = ssc[255];
    gbar(a.ctrl + MB1, CB);
    // scan stage 2: add inter-block offset, write indptr/wptr
    int boff = 0;
    for (int j = 0; j < bid; ++j) boff += a.blocksum[j];
    if (active) {
        const int run = boff + epre;
        a.indptr[i] = run;
        a.wptr[i] = run;
    }
    if (bid == 0 && tid == 0) a.indptr[N_NODES] = E_TOT;
    gbar(a.ctrl + MB2, CB);
    // scatter
    for (int e = bid * 256 + tid; e < E_TOT; e += CB * 256) {
        int s, d;
        if (e < N_EDGES) { s = a.ei[e]; d = a.ei[N_EDGES + e]; }
        else             { s = d = e - N_EDGES; }
        int pos = atomicAdd(&a.wptr[d], 1);
        a.esrc[pos] = s;
    }
}

// ---- f16 MFMA GEMM tile (verified structure, unchanged math), now a device fn ----
template <int TN, int KK>
__device__ void gemm_tile(const _Float16* __restrict__ A,
                          const _Float16* __restrict__ Bt,
                          _Float16* __restrict__ H,
                          const float* __restrict__ aw_s,
                          const float* __restrict__ aw_d,
                          float* __restrict__ als,
                          float* __restrict__ ald,
                          int HS, int N, int bx, int by, _Float16* lbh) {
    constexpr int NTB = 2 * TN;
    constexpr int NFRAG = 2 * NTB * 64;
    constexpr int NITER = NFRAG / 256;
    const int tid = threadIdx.x;
    const int wave = tid >> 6, lane = tid & 63;
    const int wr = wave >> 1, wc = wave & 1;
    const int q = lane >> 4, r = lane & 15;
    const int m0 = bx * 64 + wr * 32;
    const int n0 = by * (NTB * 16);
    size_t abase[2];
#pragma unroll
    for (int mi = 0; mi < 2; ++mi) {
        int ar = m0 + mi * 16 + r;
        if (ar >= N_NODES) ar = N_NODES - 1;   // clamp; stores guarded
        abase[mi] = (size_t)ar * KK + q * 8;
    }
    size_t gaddr[NITER];
    int loff[NITER];
#pragma unroll
    for (int j = 0; j < NITER; ++j) {
        const int f = tid + j * 256;
        const int qq = f & 3;
        const int ss = (f >> 2) & 1;
        const int rr = (f >> 3) & 15;
        const int tt = f >> 7;
        gaddr[j] = (size_t)(n0 + tt * 16 + rr) * KK + ss * 32 + qq * 8;
        const int fi = (ss * NTB + tt) * 64 + qq * 16 + rr;
        loff[j] = fi * 8 + (fi >> 4) * 8;
    }
    v4f acc[2][TN];
#pragma unroll
    for (int mi = 0; mi < 2; ++mi)
#pragma unroll
        for (int t = 0; t < TN; ++t) acc[mi][t] = (v4f){0.f, 0.f, 0.f, 0.f};

    v8h ch[NITER];
#pragma unroll
    for (int j = 0; j < NITER; ++j) ch[j] = *(const v8h*)(Bt + gaddr[j]);

#pragma unroll
    for (int kc = 0; kc < KK; kc += 64) {
        __syncthreads();
#pragma unroll
        for (int j = 0; j < NITER; ++j) *(v8h*)&lbh[loff[j]] = ch[j];
        __syncthreads();
        if (kc + 64 < KK) {
#pragma unroll
            for (int j = 0; j < NITER; ++j) ch[j] = *(const v8h*)(Bt + gaddr[j] + kc + 64);
        }
#pragma unroll
        for (int ss = 0; ss < 2; ++ss) {
            v8h ah[2];
#pragma unroll
            for (int mi = 0; mi < 2; ++mi)
                ah[mi] = *(const v8h*)(A + abase[mi] + kc + ss * 32);
#pragma unroll
            for (int t = 0; t < TN; ++t) {
                const int fib = (ss * NTB + wc * TN + t) * 4 + q;
                const int off = (fib * 16 + r) * 8 + fib * 8;
                const v8h bh = *(const v8h*)&lbh[off];
#pragma unroll
                for (int mi = 0; mi < 2; ++mi)
                    acc[mi][t] = __builtin_amdgcn_mfma_f32_16x16x32_f16(ah[mi], bh, acc[mi][t], 0, 0, 0);
            }
        }
    }
#pragma unroll
    for (int mi = 0; mi < 2; ++mi)
#pragma unroll
        for (int t = 0; t < TN; ++t)
#pragma unroll
            for (int i = 0; i < 4; ++i) {
                const int row = m0 + mi * 16 + q * 4 + i;
                if (row < N_NODES) H[(size_t)row * N + n0 + (wc * TN + t) * 16 + r] = (_Float16)acc[mi][t][i];
            }
    const int colbase = n0 + wc * TN * 16;
    const int hd = colbase >> 6;
#pragma unroll
    for (int mi = 0; mi < 2; ++mi)
#pragma unroll
        for (int i = 0; i < 4; ++i) {
            float sp = 0.f, dp = 0.f;
#pragma unroll
            for (int t = 0; t < TN; ++t) {
                const int col = colbase + t * 16 + r;
                sp += acc[mi][t][i] * aw_s[col];
                dp += acc[mi][t][i] * aw_d[col];
            }
#pragma unroll
            for (int m = 1; m < 16; m <<= 1) {
                sp += __shfl_xor(sp, m, 64);
                dp += __shfl_xor(dp, m, 64);
            }
            const int row = m0 + mi * 16 + q * 4 + i;
            if (r == 0 && row < N_NODES) {
                atomicAdd(&als[row * HS + hd], sp);
                atomicAdd(&ald[row * HS + hd], dp);
            }
        }
}

// work-stealing tile loop: t0 grabs a tile, broadcasts via LDS. Safe because
// gemm_tile's internal __syncthreads order every thread's read before t0's next write.
template <int TN, int KK>
__device__ void gemm_steal(int* cursor, int nt, int two_col,
                           const _Float16* A, const _Float16* Bt, _Float16* H,
                           const float* aws, const float* awd,
                           float* als, float* ald, int HS, int N,
                           _Float16* lbh, int* s_tile) {
    for (;;) {
        if (threadIdx.x == 0) *s_tile = atomicAdd(cursor, 1);
        __syncthreads();
        const int t = *s_tile;
        if (t >= nt) break;
        const int by = two_col ? (t & 1) : 0;   // column-pairs adjacent -> A-tile L2 reuse
        const int bx = two_col ? (t >> 1) : t;
        gemm_tile<TN, KK>(A, Bt, H, aws, awd, als, ald, HS, N, bx, by, lbh);
    }
}

// ---- GAT aggregate (4 heads): persistent, 1 wave/node, 8-deep gather chains ----
__device__ void agg4_phase(const _Float16* __restrict__ hin,
                           const float* __restrict__ als, const float* __restrict__ ald,
                           const int* __restrict__ indptr, const int* __restrict__ esrc,
                           const float* __restrict__ bias,
                           const float* __restrict__ gamma, const float* __restrict__ beta,
                           const float* __restrict__ mean, const float* __restrict__ var,
                           _Float16* __restrict__ pho, int bid) {
    const int wv = threadIdx.x >> 6;
    const int lane = threadIdx.x & 63;
    const int head = lane >> 4;
    const int c = lane * 4;
    for (int n = bid * 4 + wv; n < N_NODES; n += NB * 4) {
        const int beg = indptr[n], end = indptr[n + 1];
        const float aldn = ald[n * 4 + head];
        float4 acc = {0.f, 0.f, 0.f, 0.f};
        float sm = 0.f;
        int e = beg;
        for (; e + 7 < end; e += 8) {     // 8 independent gather chains in flight
            int s[8]; float vv[8]; v4h hh[8];
#pragma unroll
            for (int j = 0; j < 8; ++j) s[j] = esrc[e + j];
#pragma unroll
            for (int j = 0; j < 8; ++j) {
                vv[j] = als[s[j] * 4 + head] + aldn;
                hh[j] = *(const v4h*)(hin + (size_t)s[j] * 256 + c);
            }
#pragma unroll
            for (int j = 0; j < 8; ++j) {
                float v = vv[j];
                v = (v > 0.f) ? v : SLOPE * v;
                const float a0 = __expf(v);
                sm += a0;
                acc.x += a0 * (float)hh[j].x; acc.y += a0 * (float)hh[j].y;
                acc.z += a0 * (float)hh[j].z; acc.w += a0 * (float)hh[j].w;
            }
        }
        for (; e < end; ++e) {
            const int s0 = esrc[e];
            float v0 = als[s0 * 4 + head] + aldn;
            const v4h h0 = *(const v4h*)(hin + (size_t)s0 * 256 + c);
            v0 = (v0 > 0.f) ? v0 : SLOPE * v0;
            const float a0 = __expf(v0);
            sm += a0;
            acc.x += a0 * (float)h0.x; acc.y += a0 * (float)h0.y;
            acc.z += a0 * (float)h0.z; acc.w += a0 * (float)h0.w;
        }
        const float invd = 1.f / (sm + 1e-16f);
        float y[4] = {acc.x * invd, acc.y * invd, acc.z * invd, acc.w * invd};
        v4h oh;
#pragma unroll
        for (int i = 0; i < 4; ++i) {
            float t = y[i] + bias[c + i];
            t = (t - mean[c + i]) * rsqrtf(var[c + i] + EPS_BN) * gamma[c + i] + beta[c + i];
            t = fmaxf(t, 0.f);
            oh[i] = (_Float16)t;
        }
        *(v4h*)(pho + (size_t)n * 256 + c) = oh;
    }
}

// ---- GAT aggregate (1 head) + bias + ReLU + pool-scatter, persistent ----
__device__ void agg1_phase(const _Float16* __restrict__ hin,
                           const float* __restrict__ als, const float* __restrict__ ald,
                           const int* __restrict__ indptr, const int* __restrict__ esrc,
                           const float* __restrict__ bias, const int* __restrict__ batch,
                           float* __restrict__ sums, int bid) {
    const int wv = threadIdx.x >> 6;
    const int lane = threadIdx.x & 63;
    for (int n = bid * 4 + wv; n < N_NODES; n += NB * 4) {
        const int beg = indptr[n], end = indptr[n + 1];
        const float aldn = ald[n];
        float acc = 0.f, sm = 0.f;
        int e = beg;
        for (; e + 7 < end; e += 8) {
            int s[8]; float vv[8]; float hh[8];
#pragma unroll
            for (int j = 0; j < 8; ++j) s[j] = esrc[e + j];
#pragma unroll
            for (int j = 0; j < 8; ++j) {
                vv[j] = als[s[j]] + aldn;
                hh[j] = (float)hin[(size_t)s[j] * 64 + lane];
            }
#pragma unroll
            for (int j = 0; j < 8; ++j) {
                float v = vv[j];
                v = (v > 0.f) ? v : SLOPE * v;
                const float a0 = __expf(v);
                sm += a0;
                acc += a0 * hh[j];
            }
        }
        for (; e < end; ++e) {
            const int s0 = esrc[e];
            float v0 = als[s0] + aldn;
            const float h0 = (float)hin[(size_t)s0 * 64 + lane];
            v0 = (v0 > 0.f) ? v0 : SLOPE * v0;
            const float a0 = __expf(v0);
            sm += a0;
            acc += a0 * h0;
        }
        const float invd = 1.f / (sm + 1e-16f);
        const float val = fmaxf(acc * invd + bias[lane], 0.f);
        atomicAdd(&sums[batch[n] * 64 + lane], val);
    }
}

// ---------------- the megakernel ----------------
__global__ __launch_bounds__(256, 3) void k_mega(MegaArgs a) {
    __shared__ __align__(16) char smraw[17472];   // union: GEMM staging / scan / mlp hid
    __shared__ int s_tile;
    const int bid = blockIdx.x;
    const int tid = threadIdx.x;
    _Float16* lbh = (_Float16*)smraw;

    // P0: prep (weight casts, x->fp16, gstart, zero-inits)
    for (int id = bid * 256 + tid; id < PREP_IDS; id += NB * 256) prep_one(id, a);
    gbar(a.ctrl + GS0, NB);

    // P1: CSR build (96 blocks, self-synced) || GEMM1 (tile stealing; CSR blocks join late)
    if (bid < CB) csr_build(a, bid, tid, (int*)smraw);
    gemm_steal<4, 512>(a.ctrl + CUR1, 626, 1, a.xh, a.bt1, a.bufH,
                       a.a1s, a.a1d, a.als1, a.ald1, 4, 256, lbh, &s_tile);
    gbar(a.ctrl + GS1, NB);

    // P2: GAT layer-1 aggregate + BN + ReLU -> phf (== xh plane)
    agg4_phase(a.bufH, a.als1, a.ald1, a.indptr, a.esrc,
               a.b1, a.g1, a.be1, a.mu1, a.va1, a.xh, bid);
    gbar(a.ctrl + GS2, NB);

    // P3: GEMM2
    gemm_steal<4, 256>(a.ctrl + CUR2, 626, 1, a.xh, a.bt2, a.bufH,
                       a.a2s, a.a2d, a.als2, a.ald2, 4, 256, lbh, &s_tile);
    gbar(a.ctrl + GS3, NB);

    // P4: GAT layer-2 aggregate
    agg4_phase(a.bufH, a.als2, a.ald2, a.indptr, a.esrc,
               a.b2, a.g2, a.be2, a.mu2, a.va2, a.xh, bid);
    gbar(a.ctrl + GS4, NB);

    // P5: GEMM3 (64 cols, single head)
    gemm_steal<2, 256>(a.ctrl + CUR3, 313, 0, a.xh, a.bt3, a.bufH3,
                       a.a3s, a.a3d, a.als3, a.ald3, 1, 64, lbh, &s_tile);
    gbar(a.ctrl + GS5, NB);

    // P6: GAT layer-3 aggregate + ReLU + pool-scatter
    agg1_phase(a.bufH3, a.als3, a.ald3, a.indptr, a.esrc, a.b3, a.batch, a.sums, bid);
    gbar(a.ctrl + GS6, NB);

    // P7: per-graph MLP head
    if (bid < N_GRAPHS) {
        float* hid = (float*)smraw;
        const int g = bid;
        const int cntn = a.gstart[g + 1] - a.gstart[g];
        const float inv = 1.f / (float)(cntn > 0 ? cntn : 1);
        if (tid < 32) {
            float accv = a.l1b[tid];
            for (int c = 0; c < 64; ++c) accv += (a.sums[g * 64 + c] * inv) * a.l1w[c * 32 + tid];
            hid[tid] = fmaxf(accv, 0.f);
        }
        __syncthreads();
        if (tid < N_CLASSES) {
            float o = a.l2b[tid];
            for (int k = 0; k < 32; ++k) o += hid[k] * a.l2w[k * 5 + tid];
            a.out[g * 5 + tid] = o;
        }
    }
}

extern "C" void kernel_launch(void* const* d_in, const int* in_sizes, int n_in,
                              void* d_out, int out_size, void* d_ws, size_t ws_size,
                              hipStream_t stream) {
    MegaArgs a;
    a.x     = (const float*)d_in[0];
    a.ei    = (const int*)d_in[1];
    a.batch = (const int*)d_in[2];
    a.W1  = (const float*)d_in[3];
    a.a1s = (const float*)d_in[4];
    a.a1d = (const float*)d_in[5];
    a.b1  = (const float*)d_in[6];
    a.g1  = (const float*)d_in[7];
    a.be1 = (const float*)d_in[8];
    a.mu1 = (const float*)d_in[9];
    a.va1 = (const float*)d_in[10];
    a.W2  = (const float*)d_in[11];
    a.a2s = (const float*)d_in[12];
    a.a2d = (const float*)d_in[13];
    a.b2  = (const float*)d_in[14];
    a.g2  = (const float*)d_in[15];
    a.be2 = (const float*)d_in[16];
    a.mu2 = (const float*)d_in[17];
    a.va2 = (const float*)d_in[18];
    a.W3  = (const float*)d_in[19];
    a.a3s = (const float*)d_in[20];
    a.a3d = (const float*)d_in[21];
    a.b3  = (const float*)d_in[22];
    a.l1w = (const float*)d_in[23];
    a.l1b = (const float*)d_in[24];
    a.l2w = (const float*)d_in[25];
    a.l2b = (const float*)d_in[26];
    a.out = (float*)d_out;

    char* w = (char*)d_ws;
    size_t off = 0;
    auto alloc = [&](size_t bytes) -> void* {
        void* p = w + off;
        off += (bytes + 255) & ~(size_t)255;
        return p;
    };
    a.xh    = (_Float16*)alloc((size_t)N_NODES * 512 * 2);   // layer-1 A; reused as phf plane
    a.bufH  = (_Float16*)alloc((size_t)N_NODES * 256 * 2);
    a.bufH3 = (_Float16*)alloc((size_t)N_NODES * 64 * 2);
    a.bt1 = (_Float16*)alloc((size_t)512 * 256 * 2);
    a.bt2 = (_Float16*)alloc((size_t)256 * 256 * 2);
    a.bt3 = (_Float16*)alloc((size_t)256 * 64 * 2);
    a.albase = (float*)alloc((size_t)ALZ * 4);
    a.als1 = a.albase;
    a.ald1 = a.albase + 80000;
    a.als2 = a.albase + 160000;
    a.ald2 = a.albase + 240000;
    a.als3 = a.albase + 320000;
    a.ald3 = a.albase + 340000;
    a.cnt    = (int*)alloc((size_t)N_NODES * 4);
    a.wptr   = (int*)alloc((size_t)N_NODES * 4);
    a.indptr = (int*)alloc((size_t)(N_NODES + 1) * 4);
    a.esrc   = (int*)alloc((size_t)E_TOT * 4);
    a.gstart = (int*)alloc((size_t)(N_GRAPHS + 1) * 4);
    a.sums   = (float*)alloc((size_t)N_GRAPHS * 64 * 4);
    a.blocksum = (int*)alloc((size_t)CB * 4);
    a.ctrl     = (int*)alloc(256);

    // barrier slots + cursors must be zero at every graph replay
    hipMemsetAsync(a.ctrl, 0, 256, stream);
    k_mega<<<NB, 256, 0, stream>>>(a);
}

// Round 2
// 1785.168 us; speedup vs baseline: 1.0405x; 1.0405x over previous
//
#include <hip/hip_runtime.h>

#define N_NODES 20000
#define N_EDGES 320000
#define E_TOT   340000   // edges + self loops
#define N_GRAPHS 64
#define N_CLASSES 5
#define SLOPE 0.2f
#define EPS_BN 1e-5f

// persistent megakernel geometry: 768 blocks x 256 thr = 3 blocks/CU on 256 CUs.
#define NB 768
#define CB 96            // CSR-builder blocks inside phase 1
#define NCH 209          // ceil(N_NODES / CB)

typedef _Float16 v8h __attribute__((ext_vector_type(8)));  // 8 fp16 (4 VGPRs) MFMA operand
typedef float v4f __attribute__((ext_vector_type(4)));     // 4 f32 acc
typedef _Float16 v4h __attribute__((ext_vector_type(4)));  // 4 fp16 (8 B)

#define SPQ (N_NODES * 512 / 4)
#define W1E (512 * 256)
#define W2E (256 * 256)
#define W3E (256 * 64)
#define ALZ (80000 * 4 + 20000 * 2)   // als1,ald1,als2,ald2 (4x80000) + als3,ald3 (2x20000)
#define PREP_IDS (SPQ + W1E + W2E + W3E + N_NODES + N_NODES + N_GRAPHS * 64 + ALZ)

// ---- ctrl layout (ints), all zeroed per replay ----
// arrive cells: one int PER BLOCK per barrier (plain stores, no RMW):
//   GS k (k=0..6):   [k*768, k*768+768)
//   mini m (m=0..2): [5376 + m*96, ...+96)
// release words: 8 per barrier, each on its own 128B line (pollers split by bid&7):
//   REL(k) base = 5760 + k*256, word at +xcd*32   (k=0..6 GS, 7..9 mini)
#define RELBASE 5760
#define CTRL_INTS (RELBASE + 10 * 256)

struct MegaArgs {
    const float* x; const int* ei; const int* batch;
    const float* W1; const float* a1s; const float* a1d; const float* b1;
    const float* g1; const float* be1; const float* mu1; const float* va1;
    const float* W2; const float* a2s; const float* a2d; const float* b2;
    const float* g2; const float* be2; const float* mu2; const float* va2;
    const float* W3; const float* a3s; const float* a3d; const float* b3;
    const float* l1w; const float* l1b; const float* l2w; const float* l2b;
    float* out;
    _Float16* xh; _Float16* bufH; _Float16* bufH3;
    _Float16* bt1; _Float16* bt2; _Float16* bt3;
    float* als1; float* ald1; float* als2; float* ald2; float* als3; float* ald3;
    float* albase;
    int* cnt; int* wptr; int* indptr; int* esrc; int* gstart;
    float* sums; int* blocksum; int* ctrl;
};

// ---- contention-free grid barrier: per-block arrive STORE + block-0 collector ----
// arrival: 1 plain agent-scope store into a private cell (no RMW, no line ping-pong).
// collector (bid 0): 256 threads poll 768 cells spread over 24 lines, then publish
// 8 release words on 8 distinct lines; pollers split across them by bid&7.
__device__ __forceinline__ void gsync(int* ctrl, int k, int arrBase, int nb, int bid) {
    int* arr = ctrl + arrBase;
    int* rel = ctrl + RELBASE + k * 256;
    __syncthreads();
    if (threadIdx.x == 0) {
        __threadfence();   // publish this block's writes device-wide
        __hip_atomic_store(&arr[bid], 1, __ATOMIC_RELEASE, __HIP_MEMORY_SCOPE_AGENT);
    }
    if (bid == 0) {
        for (int j = (int)threadIdx.x; j < nb; j += 256) {
            while (__hip_atomic_load(&arr[j], __ATOMIC_ACQUIRE, __HIP_MEMORY_SCOPE_AGENT) == 0)
                __builtin_amdgcn_s_sleep(2);
        }
        __syncthreads();
        if (threadIdx.x < 8) {
            __threadfence();
            __hip_atomic_store(&rel[threadIdx.x * 32], 1, __ATOMIC_RELEASE, __HIP_MEMORY_SCOPE_AGENT);
        }
    } else if (threadIdx.x == 0) {
        int* myrel = &rel[(bid & 7) * 32];
        while (__hip_atomic_load(myrel, __ATOMIC_ACQUIRE, __HIP_MEMORY_SCOPE_AGENT) == 0)
            __builtin_amdgcn_s_sleep(2);
        __threadfence();   // invalidate stale cached lines before post-barrier reads
    }
    __syncthreads();
}

// ---- grid-stride prep work item (identical math to verified k_prep) ----
__device__ __forceinline__ void prep_one(int id, const MegaArgs& a) {
    if (id < SPQ) {
        const float4 v = *(const float4*)(a.x + (size_t)id * 4);
        v4h h;
        h.x = (_Float16)v.x; h.y = (_Float16)v.y; h.z = (_Float16)v.z; h.w = (_Float16)v.w;
        *(v4h*)(a.xh + (size_t)id * 4) = h;
        return;
    }
    id -= SPQ;
    if (id < W1E) {
        const int K = 512, N = 256;
        int n = id / K, k = id - n * K;
        a.bt1[id] = (_Float16)a.W1[(size_t)k * N + n];
        return;
    }
    id -= W1E;
    if (id < W2E) {
        const int K = 256, N = 256;
        int n = id / K, k = id - n * K;
        a.bt2[id] = (_Float16)a.W2[(size_t)k * N + n];
        return;
    }
    id -= W2E;
    if (id < W3E) {
        const int K = 256, N = 64;
        int n = id / K, k = id - n * K;
        a.bt3[id] = (_Float16)a.W3[(size_t)k * N + n];
        return;
    }
    id -= W3E;
    if (id < N_NODES) {
        int i = id;
        int b = a.batch[i];
        if (i == 0) {
            for (int g = 0; g <= b; ++g) a.gstart[g] = 0;
        } else {
            int p = a.batch[i - 1];
            for (int g = p + 1; g <= b; ++g) a.gstart[g] = i;
        }
        if (i == N_NODES - 1) {
            for (int g = b + 1; g <= N_GRAPHS; ++g) a.gstart[g] = N_NODES;
        }
        return;
    }
    id -= N_NODES;
    if (id < N_NODES) { a.cnt[id] = 0; return; }
    id -= N_NODES;
    if (id < N_GRAPHS * 64) { a.sums[id] = 0.f; return; }
    id -= N_GRAPHS * 64;
    if (id < ALZ) a.albase[id] = 0.f;
}

// ---- CSR build on CB blocks (count -> two-level scan -> scatter), self-synced ----
__device__ void csr_build(const MegaArgs& a, int bid, int tid, int* ssc) {
    // count
    for (int e = bid * 256 + tid; e < E_TOT; e += CB * 256) {
        int d = (e < N_EDGES) ? a.ei[N_EDGES + e] : (e - N_EDGES);
        atomicAdd(&a.cnt[d], 1);
    }
    gsync(a.ctrl, 7, 5376 + 0 * 96, CB, bid);
    // scan stage 1: block-local scan over NCH contiguous nodes (1 node / thread)
    const int i = bid * NCH + tid;
    const int active = (tid < NCH && i < N_NODES);
    int ls = active ? a.cnt[i] : 0;
    ssc[tid] = ls;
    __syncthreads();
    for (int off = 1; off < 256; off <<= 1) {
        int v = (tid >= off) ? ssc[tid - off] : 0;
        __syncthreads();
        ssc[tid] += v;
        __syncthreads();
    }
    const int epre = ssc[tid] - ls;       // exclusive prefix within block chunk
    if (tid == 255) a.blocksum[bid] = ssc[255];
    gsync(a.ctrl, 8, 5376 + 1 * 96, CB, bid);
    // scan stage 2: add inter-block offset, write indptr/wptr
    int boff = 0;
    for (int j = 0; j < bid; ++j) boff += a.blocksum[j];
    if (active) {
        const int run = boff + epre;
        a.indptr[i] = run;
        a.wptr[i] = run;
    }
    if (bid == 0 && tid == 0) a.indptr[N_NODES] = E_TOT;
    gsync(a.ctrl, 9, 5376 + 2 * 96, CB, bid);
    // scatter
    for (int e = bid * 256 + tid; e < E_TOT; e += CB * 256) {
        int s, d;
        if (e < N_EDGES) { s = a.ei[e]; d = a.ei[N_EDGES + e]; }
        else             { s = d = e - N_EDGES; }
        int pos = atomicAdd(&a.wptr[d], 1);
        a.esrc[pos] = s;
    }
}

// ---- f16 MFMA GEMM tile (verified structure, unchanged math) ----
template <int TN, int KK>
__device__ void gemm_tile(const _Float16* __restrict__ A,
                          const _Float16* __restrict__ Bt,
                          _Float16* __restrict__ H,
                          const float* __restrict__ aw_s,
                          const float* __restrict__ aw_d,
                          float* __restrict__ als,
                          float* __restrict__ ald,
                          int HS, int N, int bx, int by, _Float16* lbh) {
    constexpr int NTB = 2 * TN;
    constexpr int NFRAG = 2 * NTB * 64;
    constexpr int NITER = NFRAG / 256;
    const int tid = threadIdx.x;
    const int wave = tid >> 6, lane = tid & 63;
    const int wr = wave >> 1, wc = wave & 1;
    const int q = lane >> 4, r = lane & 15;
    const int m0 = bx * 64 + wr * 32;
    const int n0 = by * (NTB * 16);
    size_t abase[2];
#pragma unroll
    for (int mi = 0; mi < 2; ++mi) {
        int ar = m0 + mi * 16 + r;
        if (ar >= N_NODES) ar = N_NODES - 1;   // clamp; stores guarded
        abase[mi] = (size_t)ar * KK + q * 8;
    }
    size_t gaddr[NITER];
    int loff[NITER];
#pragma unroll
    for (int j = 0; j < NITER; ++j) {
        const int f = tid + j * 256;
        const int qq = f & 3;
        const int ss = (f >> 2) & 1;
        const int rr = (f >> 3) & 15;
        const int tt = f >> 7;
        gaddr[j] = (size_t)(n0 + tt * 16 + rr) * KK + ss * 32 + qq * 8;
        const int fi = (ss * NTB + tt) * 64 + qq * 16 + rr;
        loff[j] = fi * 8 + (fi >> 4) * 8;
    }
    v4f acc[2][TN];
#pragma unroll
    for (int mi = 0; mi < 2; ++mi)
#pragma unroll
        for (int t = 0; t < TN; ++t) acc[mi][t] = (v4f){0.f, 0.f, 0.f, 0.f};

    v8h ch[NITER];
#pragma unroll
    for (int j = 0; j < NITER; ++j) ch[j] = *(const v8h*)(Bt + gaddr[j]);

#pragma unroll
    for (int kc = 0; kc < KK; kc += 64) {
        __syncthreads();
#pragma unroll
        for (int j = 0; j < NITER; ++j) *(v8h*)&lbh[loff[j]] = ch[j];
        __syncthreads();
        if (kc + 64 < KK) {
#pragma unroll
            for (int j = 0; j < NITER; ++j) ch[j] = *(const v8h*)(Bt + gaddr[j] + kc + 64);
        }
#pragma unroll
        for (int ss = 0; ss < 2; ++ss) {
            v8h ah[2];
#pragma unroll
            for (int mi = 0; mi < 2; ++mi)
                ah[mi] = *(const v8h*)(A + abase[mi] + kc + ss * 32);
#pragma unroll
            for (int t = 0; t < TN; ++t) {
                const int fib = (ss * NTB + wc * TN + t) * 4 + q;
                const int off = (fib * 16 + r) * 8 + fib * 8;
                const v8h bh = *(const v8h*)&lbh[off];
#pragma unroll
                for (int mi = 0; mi < 2; ++mi)
                    acc[mi][t] = __builtin_amdgcn_mfma_f32_16x16x32_f16(ah[mi], bh, acc[mi][t], 0, 0, 0);
            }
        }
    }
#pragma unroll
    for (int mi = 0; mi < 2; ++mi)
#pragma unroll
        for (int t = 0; t < TN; ++t)
#pragma unroll
            for (int i = 0; i < 4; ++i) {
                const int row = m0 + mi * 16 + q * 4 + i;
                if (row < N_NODES) H[(size_t)row * N + n0 + (wc * TN + t) * 16 + r] = (_Float16)acc[mi][t][i];
            }
    const int colbase = n0 + wc * TN * 16;
    const int hd = colbase >> 6;
#pragma unroll
    for (int mi = 0; mi < 2; ++mi)
#pragma unroll
        for (int i = 0; i < 4; ++i) {
            float sp = 0.f, dp = 0.f;
#pragma unroll
            for (int t = 0; t < TN; ++t) {
                const int col = colbase + t * 16 + r;
                sp += acc[mi][t][i] * aw_s[col];
                dp += acc[mi][t][i] * aw_d[col];
            }
#pragma unroll
            for (int m = 1; m < 16; m <<= 1) {
                sp += __shfl_xor(sp, m, 64);
                dp += __shfl_xor(dp, m, 64);
            }
            const int row = m0 + mi * 16 + q * 4 + i;
            if (r == 0 && row < N_NODES) {
                atomicAdd(&als[row * HS + hd], sp);
                atomicAdd(&ald[row * HS + hd], dp);
            }
        }
}

// ---- GAT aggregate (4 heads): persistent, 1 wave/node, 8-deep gather chains ----
__device__ void agg4_phase(const _Float16* __restrict__ hin,
                           const float* __restrict__ als, const float* __restrict__ ald,
                           const int* __restrict__ indptr, const int* __restrict__ esrc,
                           const float* __restrict__ bias,
                           const float* __restrict__ gamma, const float* __restrict__ beta,
                           const float* __restrict__ mean, const float* __restrict__ var,
                           _Float16* __restrict__ pho, int bid) {
    const int wv = threadIdx.x >> 6;
    const int lane = threadIdx.x & 63;
    const int head = lane >> 4;
    const int c = lane * 4;
    for (int n = bid * 4 + wv; n < N_NODES; n += NB * 4) {
        const int beg = indptr[n], end = indptr[n + 1];
        const float aldn = ald[n * 4 + head];
        float4 acc = {0.f, 0.f, 0.f, 0.f};
        float sm = 0.f;
        int e = beg;
        for (; e + 7 < end; e += 8) {     // 8 independent gather chains in flight
            int s[8]; float vv[8]; v4h hh[8];
#pragma unroll
            for (int j = 0; j < 8; ++j) s[j] = esrc[e + j];
#pragma unroll
            for (int j = 0; j < 8; ++j) {
                vv[j] = als[s[j] * 4 + head] + aldn;
                hh[j] = *(const v4h*)(hin + (size_t)s[j] * 256 + c);
            }
#pragma unroll
            for (int j = 0; j < 8; ++j) {
                float v = vv[j];
                v = (v > 0.f) ? v : SLOPE * v;
                const float a0 = __expf(v);
                sm += a0;
                acc.x += a0 * (float)hh[j].x; acc.y += a0 * (float)hh[j].y;
                acc.z += a0 * (float)hh[j].z; acc.w += a0 * (float)hh[j].w;
            }
        }
        for (; e < end; ++e) {
            const int s0 = esrc[e];
            float v0 = als[s0 * 4 + head] + aldn;
            const v4h h0 = *(const v4h*)(hin + (size_t)s0 * 256 + c);
            v0 = (v0 > 0.f) ? v0 : SLOPE * v0;
            const float a0 = __expf(v0);
            sm += a0;
            acc.x += a0 * (float)h0.x; acc.y += a0 * (float)h0.y;
            acc.z += a0 * (float)h0.z; acc.w += a0 * (float)h0.w;
        }
        const float invd = 1.f / (sm + 1e-16f);
        float y[4] = {acc.x * invd, acc.y * invd, acc.z * invd, acc.w * invd};
        v4h oh;
#pragma unroll
        for (int i = 0; i < 4; ++i) {
            float t = y[i] + bias[c + i];
            t = (t - mean[c + i]) * rsqrtf(var[c + i] + EPS_BN) * gamma[c + i] + beta[c + i];
            t = fmaxf(t, 0.f);
            oh[i] = (_Float16)t;
        }
        *(v4h*)(pho + (size_t)n * 256 + c) = oh;
    }
}

// ---- GAT aggregate (1 head) + bias + ReLU + pool-scatter, persistent ----
__device__ void agg1_phase(const _Float16* __restrict__ hin,
                           const float* __restrict__ als, const float* __restrict__ ald,
                           const int* __restrict__ indptr, const int* __restrict__ esrc,
                           const float* __restrict__ bias, const int* __restrict__ batch,
                           float* __restrict__ sums, int bid) {
    const int wv = threadIdx.x >> 6;
    const int lane = threadIdx.x & 63;
    for (int n = bid * 4 + wv; n < N_NODES; n += NB * 4) {
        const int beg = indptr[n], end = indptr[n + 1];
        const float aldn = ald[n];
        float acc = 0.f, sm = 0.f;
        int e = beg;
        for (; e + 7 < end; e += 8) {
            int s[8]; float vv[8]; float hh[8];
#pragma unroll
            for (int j = 0; j < 8; ++j) s[j] = esrc[e + j];
#pragma unroll
            for (int j = 0; j < 8; ++j) {
                vv[j] = als[s[j]] + aldn;
                hh[j] = (float)hin[(size_t)s[j] * 64 + lane];
            }
#pragma unroll
            for (int j = 0; j < 8; ++j) {
                float v = vv[j];
                v = (v > 0.f) ? v : SLOPE * v;
                const float a0 = __expf(v);
                sm += a0;
                acc += a0 * hh[j];
            }
        }
        for (; e < end; ++e) {
            const int s0 = esrc[e];
            float v0 = als[s0] + aldn;
            const float h0 = (float)hin[(size_t)s0 * 64 + lane];
            v0 = (v0 > 0.f) ? v0 : SLOPE * v0;
            const float a0 = __expf(v0);
            sm += a0;
            acc += a0 * h0;
        }
        const float invd = 1.f / (sm + 1e-16f);
        const float val = fmaxf(acc * invd + bias[lane], 0.f);
        atomicAdd(&sums[batch[n] * 64 + lane], val);
    }
}

// ---------------- the megakernel ----------------
__global__ __launch_bounds__(256, 3) void k_mega(MegaArgs a) {
    __shared__ __align__(16) char smraw[17472];   // union: GEMM staging / scan / mlp hid
    const int bid = blockIdx.x;
    const int tid = threadIdx.x;
    _Float16* lbh = (_Float16*)smraw;

    // P0: prep (weight casts, x->fp16, gstart, zero-inits)
    for (int id = bid * 256 + tid; id < PREP_IDS; id += NB * 256) prep_one(id, a);
    gsync(a.ctrl, 0, 0 * 768, NB, bid);

    // P1: CSR build (96 blocks, self-synced) || GEMM1 static 1 tile/block on the rest
    if (bid < CB) {
        csr_build(a, bid, tid, (int*)smraw);
    } else {
        const int t = bid - CB;
        if (t < 626) gemm_tile<4, 512>(a.xh, a.bt1, a.bufH, a.a1s, a.a1d,
                                       a.als1, a.ald1, 4, 256, t >> 1, t & 1, lbh);
    }
    gsync(a.ctrl, 1, 1 * 768, NB, bid);

    // P2: GAT layer-1 aggregate + BN + ReLU -> phf (== xh plane)
    agg4_phase(a.bufH, a.als1, a.ald1, a.indptr, a.esrc,
               a.b1, a.g1, a.be1, a.mu1, a.va1, a.xh, bid);
    gsync(a.ctrl, 2, 2 * 768, NB, bid);

    // P3: GEMM2, static 1 tile/block
    if (bid < 626) gemm_tile<4, 256>(a.xh, a.bt2, a.bufH, a.a2s, a.a2d,
                                     a.als2, a.ald2, 4, 256, bid >> 1, bid & 1, lbh);
    gsync(a.ctrl, 3, 3 * 768, NB, bid);

    // P4: GAT layer-2 aggregate
    agg4_phase(a.bufH, a.als2, a.ald2, a.indptr, a.esrc,
               a.b2, a.g2, a.be2, a.mu2, a.va2, a.xh, bid);
    gsync(a.ctrl, 4, 4 * 768, NB, bid);

    // P5: GEMM3 (64 cols, single head), static 1 tile/block
    if (bid < 313) gemm_tile<2, 256>(a.xh, a.bt3, a.bufH3, a.a3s, a.a3d,
                                     a.als3, a.ald3, 1, 64, bid, 0, lbh);
    gsync(a.ctrl, 5, 5 * 768, NB, bid);

    // P6: GAT layer-3 aggregate + ReLU + pool-scatter
    agg1_phase(a.bufH3, a.als3, a.ald3, a.indptr, a.esrc, a.b3, a.batch, a.sums, bid);
    gsync(a.ctrl, 6, 6 * 768, NB, bid);

    // P7: per-graph MLP head
    if (bid < N_GRAPHS) {
        float* hid = (float*)smraw;
        const int g = bid;
        const int cntn = a.gstart[g + 1] - a.gstart[g];
        const float inv = 1.f / (float)(cntn > 0 ? cntn : 1);
        if (tid < 32) {
            float accv = a.l1b[tid];
            for (int c = 0; c < 64; ++c) accv += (a.sums[g * 64 + c] * inv) * a.l1w[c * 32 + tid];
            hid[tid] = fmaxf(accv, 0.f);
        }
        __syncthreads();
        if (tid < N_CLASSES) {
            float o = a.l2b[tid];
            for (int k = 0; k < 32; ++k) o += hid[k] * a.l2w[k * 5 + tid];
            a.out[g * 5 + tid] = o;
        }
    }
}

extern "C" void kernel_launch(void* const* d_in, const int* in_sizes, int n_in,
                              void* d_out, int out_size, void* d_ws, size_t ws_size,
                              hipStream_t stream) {
    MegaArgs a;
    a.x     = (const float*)d_in[0];
    a.ei    = (const int*)d_in[1];
    a.batch = (const int*)d_in[2];
    a.W1  = (const float*)d_in[3];
    a.a1s = (const float*)d_in[4];
    a.a1d = (const float*)d_in[5];
    a.b1  = (const float*)d_in[6];
    a.g1  = (const float*)d_in[7];
    a.be1 = (const float*)d_in[8];
    a.mu1 = (const float*)d_in[9];
    a.va1 = (const float*)d_in[10];
    a.W2  = (const float*)d_in[11];
    a.a2s = (const float*)d_in[12];
    a.a2d = (const float*)d_in[13];
    a.b2  = (const float*)d_in[14];
    a.g2  = (const float*)d_in[15];
    a.be2 = (const float*)d_in[16];
    a.mu2 = (const float*)d_in[17];
    a.va2 = (const float*)d_in[18];
    a.W3  = (const float*)d_in[19];
    a.a3s = (const float*)d_in[20];
    a.a3d = (const float*)d_in[21];
    a.b3  = (const float*)d_in[22];
    a.l1w = (const float*)d_in[23];
    a.l1b = (const float*)d_in[24];
    a.l2w = (const float*)d_in[25];
    a.l2b = (const float*)d_in[26];
    a.out = (float*)d_out;

    char* w = (char*)d_ws;
    size_t off = 0;
    auto alloc = [&](size_t bytes) -> void* {
        void* p = w + off;
        off += (bytes + 255) & ~(size_t)255;
        return p;
    };
    a.xh    = (_Float16*)alloc((size_t)N_NODES * 512 * 2);   // layer-1 A; reused as phf plane
    a.bufH  = (_Float16*)alloc((size_t)N_NODES * 256 * 2);
    a.bufH3 = (_Float16*)alloc((size_t)N_NODES * 64 * 2);
    a.bt1 = (_Float16*)alloc((size_t)512 * 256 * 2);
    a.bt2 = (_Float16*)alloc((size_t)256 * 256 * 2);
    a.bt3 = (_Float16*)alloc((size_t)256 * 64 * 2);
    a.albase = (float*)alloc((size_t)ALZ * 4);
    a.als1 = a.albase;
    a.ald1 = a.albase + 80000;
    a.als2 = a.albase + 160000;
    a.ald2 = a.albase + 240000;
    a.als3 = a.albase + 320000;
    a.ald3 = a.albase + 340000;
    a.cnt    = (int*)alloc((size_t)N_NODES * 4);
    a.wptr   = (int*)alloc((size_t)N_NODES * 4);
    a.indptr = (int*)alloc((size_t)(N_NODES + 1) * 4);
    a.esrc   = (int*)alloc((size_t)E_TOT * 4);
    a.gstart = (int*)alloc((size_t)(N_GRAPHS + 1) * 4);
    a.sums   = (float*)alloc((size_t)N_GRAPHS * 64 * 4);
    a.blocksum = (int*)alloc((size_t)CB * 4);
    a.ctrl     = (int*)alloc((size_t)CTRL_INTS * 4);

    // barrier cells + release words must be zero at every graph replay
    hipMemsetAsync(a.ctrl, 0, (size_t)CTRL_INTS * 4, stream);
    k_mega<<<NB, 256, 0, stream>>>(a);
}

// Round 3
// 468.757 us; speedup vs baseline: 3.9627x; 3.8083x over previous
//
#include <hip/hip_runtime.h>

#define N_NODES 20000
#define N_EDGES 320000
#define E_TOT   340000   // edges + self loops
#define N_GRAPHS 64
#define N_CLASSES 5
#define SLOPE 0.2f
#define EPS_BN 1e-5f

// persistent megakernel geometry: 768 blocks x 256 thr = 3 blocks/CU on 256 CUs.
#define NB 768
#define CB 96            // CSR-builder blocks inside phase 1
#define NCH 209          // ceil(N_NODES / CB)

typedef _Float16 v8h __attribute__((ext_vector_type(8)));  // 8 fp16 (4 VGPRs) MFMA operand
typedef float v4f __attribute__((ext_vector_type(4)));     // 4 f32 acc
typedef _Float16 v4h __attribute__((ext_vector_type(4)));  // 4 fp16 (8 B)

#define SPQ (N_NODES * 512 / 4)
#define W1E (512 * 256)
#define W2E (256 * 256)
#define W3E (256 * 64)
#define ALZ (80000 * 4 + 20000 * 2)   // als1,ald1,als2,ald2 (4x80000) + als3,ald3 (2x20000)
#define PREP_IDS (SPQ + W1E + W2E + W3E + N_NODES + N_NODES + N_GRAPHS * 64 + ALZ)

// ---- ctrl layout (ints), all zeroed per replay ----
#define RELBASE 5760
#define CTRL_INTS (RELBASE + 10 * 256)

struct MegaArgs {
    const float* x; const int* ei; const int* batch;
    const float* W1; const float* a1s; const float* a1d; const float* b1;
    const float* g1; const float* be1; const float* mu1; const float* va1;
    const float* W2; const float* a2s; const float* a2d; const float* b2;
    const float* g2; const float* be2; const float* mu2; const float* va2;
    const float* W3; const float* a3s; const float* a3d; const float* b3;
    const float* l1w; const float* l1b; const float* l2w; const float* l2b;
    float* out;
    _Float16* xh; _Float16* bufH; _Float16* bufH3;
    _Float16* bt1; _Float16* bt2; _Float16* bt3;
    float* als1; float* ald1; float* als2; float* ald2; float* als3; float* ald3;
    float* albase;
    int* cnt; int* wptr; int* indptr; int* esrc; int* gstart;
    float* sums; int* blocksum; int* ctrl;
};

// ---- grid barrier, RELAXED polling (no per-iteration buffer_inv / L2 nuke) ----
// arrival: one agent release-fence (wbl2, required: publish dirty data to the
// coherence point) + relaxed flag store. Pollers use RELAXED loads (lowered to a
// single coherence-point load, NO cache invalidate), then ONE acquire fence after
// the flag flips. This removes the per-poll-iteration buffer_inv that invalidated
// the XCD L2s continuously while laggard blocks were still computing.
__device__ __forceinline__ void gsync(int* ctrl, int k, int arrBase, int nb, int bid) {
    int* arr = ctrl + arrBase;
    int* rel = ctrl + RELBASE + k * 256;
    __syncthreads();
    if (threadIdx.x == 0) {
        __builtin_amdgcn_fence(__ATOMIC_RELEASE, "agent");   // write back dirty L2 once
        __hip_atomic_store(&arr[bid], 1, __ATOMIC_RELAXED, __HIP_MEMORY_SCOPE_AGENT);
    }
    if (bid == 0) {
        for (int j = (int)threadIdx.x; j < nb; j += 256) {
            while (__hip_atomic_load(&arr[j], __ATOMIC_RELAXED, __HIP_MEMORY_SCOPE_AGENT) == 0)
                __builtin_amdgcn_s_sleep(8);
        }
        __syncthreads();
        if (threadIdx.x < 8) {
            __hip_atomic_store(&rel[threadIdx.x * 32], 1, __ATOMIC_RELAXED, __HIP_MEMORY_SCOPE_AGENT);
        }
        if (threadIdx.x == 0)
            __builtin_amdgcn_fence(__ATOMIC_ACQUIRE, "agent");  // one inv before post-barrier reads
    } else if (threadIdx.x == 0) {
        int* myrel = &rel[(bid & 7) * 32];
        while (__hip_atomic_load(myrel, __ATOMIC_RELAXED, __HIP_MEMORY_SCOPE_AGENT) == 0)
            __builtin_amdgcn_s_sleep(8);
        __builtin_amdgcn_fence(__ATOMIC_ACQUIRE, "agent");      // one inv before post-barrier reads
    }
    __syncthreads();
}

// ---- grid-stride prep work item (identical math to verified k_prep) ----
__device__ __forceinline__ void prep_one(int id, const MegaArgs& a) {
    if (id < SPQ) {
        const float4 v = *(const float4*)(a.x + (size_t)id * 4);
        v4h h;
        h.x = (_Float16)v.x; h.y = (_Float16)v.y; h.z = (_Float16)v.z; h.w = (_Float16)v.w;
        *(v4h*)(a.xh + (size_t)id * 4) = h;
        return;
    }
    id -= SPQ;
    if (id < W1E) {
        const int K = 512, N = 256;
        int n = id / K, k = id - n * K;
        a.bt1[id] = (_Float16)a.W1[(size_t)k * N + n];
        return;
    }
    id -= W1E;
    if (id < W2E) {
        const int K = 256, N = 256;
        int n = id / K, k = id - n * K;
        a.bt2[id] = (_Float16)a.W2[(size_t)k * N + n];
        return;
    }
    id -= W2E;
    if (id < W3E) {
        const int K = 256, N = 64;
        int n = id / K, k = id - n * K;
        a.bt3[id] = (_Float16)a.W3[(size_t)k * N + n];
        return;
    }
    id -= W3E;
    if (id < N_NODES) {
        int i = id;
        int b = a.batch[i];
        if (i == 0) {
            for (int g = 0; g <= b; ++g) a.gstart[g] = 0;
        } else {
            int p = a.batch[i - 1];
            for (int g = p + 1; g <= b; ++g) a.gstart[g] = i;
        }
        if (i == N_NODES - 1) {
            for (int g = b + 1; g <= N_GRAPHS; ++g) a.gstart[g] = N_NODES;
        }
        return;
    }
    id -= N_NODES;
    if (id < N_NODES) { a.cnt[id] = 0; return; }
    id -= N_NODES;
    if (id < N_GRAPHS * 64) { a.sums[id] = 0.f; return; }
    id -= N_GRAPHS * 64;
    if (id < ALZ) a.albase[id] = 0.f;
}

// ---- CSR build on CB blocks (count -> two-level scan -> scatter), self-synced ----
__device__ void csr_build(const MegaArgs& a, int bid, int tid, int* ssc) {
    // count
    for (int e = bid * 256 + tid; e < E_TOT; e += CB * 256) {
        int d = (e < N_EDGES) ? a.ei[N_EDGES + e] : (e - N_EDGES);
        atomicAdd(&a.cnt[d], 1);
    }
    gsync(a.ctrl, 7, 5376 + 0 * 96, CB, bid);
    // scan stage 1: block-local scan over NCH contiguous nodes (1 node / thread)
    const int i = bid * NCH + tid;
    const int active = (tid < NCH && i < N_NODES);
    int ls = active ? a.cnt[i] : 0;
    ssc[tid] = ls;
    __syncthreads();
    for (int off = 1; off < 256; off <<= 1) {
        int v = (tid >= off) ? ssc[tid - off] : 0;
        __syncthreads();
        ssc[tid] += v;
        __syncthreads();
    }
    const int epre = ssc[tid] - ls;       // exclusive prefix within block chunk
    if (tid == 255) a.blocksum[bid] = ssc[255];
    gsync(a.ctrl, 8, 5376 + 1 * 96, CB, bid);
    // scan stage 2: add inter-block offset, write indptr/wptr
    int boff = 0;
    for (int j = 0; j < bid; ++j) boff += a.blocksum[j];
    if (active) {
        const int run = boff + epre;
        a.indptr[i] = run;
        a.wptr[i] = run;
    }
    if (bid == 0 && tid == 0) a.indptr[N_NODES] = E_TOT;
    gsync(a.ctrl, 9, 5376 + 2 * 96, CB, bid);
    // scatter
    for (int e = bid * 256 + tid; e < E_TOT; e += CB * 256) {
        int s, d;
        if (e < N_EDGES) { s = a.ei[e]; d = a.ei[N_EDGES + e]; }
        else             { s = d = e - N_EDGES; }
        int pos = atomicAdd(&a.wptr[d], 1);
        a.esrc[pos] = s;
    }
}

// ---- f16 MFMA GEMM tile (verified structure, unchanged math) ----
template <int TN, int KK>
__device__ void gemm_tile(const _Float16* __restrict__ A,
                          const _Float16* __restrict__ Bt,
                          _Float16* __restrict__ H,
                          const float* __restrict__ aw_s,
                          const float* __restrict__ aw_d,
                          float* __restrict__ als,
                          float* __restrict__ ald,
                          int HS, int N, int bx, int by, _Float16* lbh) {
    constexpr int NTB = 2 * TN;
    constexpr int NFRAG = 2 * NTB * 64;
    constexpr int NITER = NFRAG / 256;
    const int tid = threadIdx.x;
    const int wave = tid >> 6, lane = tid & 63;
    const int wr = wave >> 1, wc = wave & 1;
    const int q = lane >> 4, r = lane & 15;
    const int m0 = bx * 64 + wr * 32;
    const int n0 = by * (NTB * 16);
    size_t abase[2];
#pragma unroll
    for (int mi = 0; mi < 2; ++mi) {
        int ar = m0 + mi * 16 + r;
        if (ar >= N_NODES) ar = N_NODES - 1;   // clamp; stores guarded
        abase[mi] = (size_t)ar * KK + q * 8;
    }
    size_t gaddr[NITER];
    int loff[NITER];
#pragma unroll
    for (int j = 0; j < NITER; ++j) {
        const int f = tid + j * 256;
        const int qq = f & 3;
        const int ss = (f >> 2) & 1;
        const int rr = (f >> 3) & 15;
        const int tt = f >> 7;
        gaddr[j] = (size_t)(n0 + tt * 16 + rr) * KK + ss * 32 + qq * 8;
        const int fi = (ss * NTB + tt) * 64 + qq * 16 + rr;
        loff[j] = fi * 8 + (fi >> 4) * 8;
    }
    v4f acc[2][TN];
#pragma unroll
    for (int mi = 0; mi < 2; ++mi)
#pragma unroll
        for (int t = 0; t < TN; ++t) acc[mi][t] = (v4f){0.f, 0.f, 0.f, 0.f};

    v8h ch[NITER];
#pragma unroll
    for (int j = 0; j < NITER; ++j) ch[j] = *(const v8h*)(Bt + gaddr[j]);

#pragma unroll
    for (int kc = 0; kc < KK; kc += 64) {
        __syncthreads();
#pragma unroll
        for (int j = 0; j < NITER; ++j) *(v8h*)&lbh[loff[j]] = ch[j];
        __syncthreads();
        if (kc + 64 < KK) {
#pragma unroll
            for (int j = 0; j < NITER; ++j) ch[j] = *(const v8h*)(Bt + gaddr[j] + kc + 64);
        }
#pragma unroll
        for (int ss = 0; ss < 2; ++ss) {
            v8h ah[2];
#pragma unroll
            for (int mi = 0; mi < 2; ++mi)
                ah[mi] = *(const v8h*)(A + abase[mi] + kc + ss * 32);
#pragma unroll
            for (int t = 0; t < TN; ++t) {
                const int fib = (ss * NTB + wc * TN + t) * 4 + q;
                const int off = (fib * 16 + r) * 8 + fib * 8;
                const v8h bh = *(const v8h*)&lbh[off];
#pragma unroll
                for (int mi = 0; mi < 2; ++mi)
                    acc[mi][t] = __builtin_amdgcn_mfma_f32_16x16x32_f16(ah[mi], bh, acc[mi][t], 0, 0, 0);
            }
        }
    }
#pragma unroll
    for (int mi = 0; mi < 2; ++mi)
#pragma unroll
        for (int t = 0; t < TN; ++t)
#pragma unroll
            for (int i = 0; i < 4; ++i) {
                const int row = m0 + mi * 16 + q * 4 + i;
                if (row < N_NODES) H[(size_t)row * N + n0 + (wc * TN + t) * 16 + r] = (_Float16)acc[mi][t][i];
            }
    const int colbase = n0 + wc * TN * 16;
    const int hd = colbase >> 6;
#pragma unroll
    for (int mi = 0; mi < 2; ++mi)
#pragma unroll
        for (int i = 0; i < 4; ++i) {
            float sp = 0.f, dp = 0.f;
#pragma unroll
            for (int t = 0; t < TN; ++t) {
                const int col = colbase + t * 16 + r;
                sp += acc[mi][t][i] * aw_s[col];
                dp += acc[mi][t][i] * aw_d[col];
            }
#pragma unroll
            for (int m = 1; m < 16; m <<= 1) {
                sp += __shfl_xor(sp, m, 64);
                dp += __shfl_xor(dp, m, 64);
            }
            const int row = m0 + mi * 16 + q * 4 + i;
            if (r == 0 && row < N_NODES) {
                atomicAdd(&als[row * HS + hd], sp);
                atomicAdd(&ald[row * HS + hd], dp);
            }
        }
}

// ---- GAT aggregate (4 heads): persistent, 1 wave/node, 8-deep gather chains ----
__device__ void agg4_phase(const _Float16* __restrict__ hin,
                           const float* __restrict__ als, const float* __restrict__ ald,
                           const int* __restrict__ indptr, const int* __restrict__ esrc,
                           const float* __restrict__ bias,
                           const float* __restrict__ gamma, const float* __restrict__ beta,
                           const float* __restrict__ mean, const float* __restrict__ var,
                           _Float16* __restrict__ pho, int bid) {
    const int wv = threadIdx.x >> 6;
    const int lane = threadIdx.x & 63;
    const int head = lane >> 4;
    const int c = lane * 4;
    for (int n = bid * 4 + wv; n < N_NODES; n += NB * 4) {
        const int beg = indptr[n], end = indptr[n + 1];
        const float aldn = ald[n * 4 + head];
        float4 acc = {0.f, 0.f, 0.f, 0.f};
        float sm = 0.f;
        int e = beg;
        for (; e + 7 < end; e += 8) {     // 8 independent gather chains in flight
            int s[8]; float vv[8]; v4h hh[8];
#pragma unroll
            for (int j = 0; j < 8; ++j) s[j] = esrc[e + j];
#pragma unroll
            for (int j = 0; j < 8; ++j) {
                vv[j] = als[s[j] * 4 + head] + aldn;
                hh[j] = *(const v4h*)(hin + (size_t)s[j] * 256 + c);
            }
#pragma unroll
            for (int j = 0; j < 8; ++j) {
                float v = vv[j];
                v = (v > 0.f) ? v : SLOPE * v;
                const float a0 = __expf(v);
                sm += a0;
                acc.x += a0 * (float)hh[j].x; acc.y += a0 * (float)hh[j].y;
                acc.z += a0 * (float)hh[j].z; acc.w += a0 * (float)hh[j].w;
            }
        }
        for (; e < end; ++e) {
            const int s0 = esrc[e];
            float v0 = als[s0 * 4 + head] + aldn;
            const v4h h0 = *(const v4h*)(hin + (size_t)s0 * 256 + c);
            v0 = (v0 > 0.f) ? v0 : SLOPE * v0;
            const float a0 = __expf(v0);
            sm += a0;
            acc.x += a0 * (float)h0.x; acc.y += a0 * (float)h0.y;
            acc.z += a0 * (float)h0.z; acc.w += a0 * (float)h0.w;
        }
        const float invd = 1.f / (sm + 1e-16f);
        float y[4] = {acc.x * invd, acc.y * invd, acc.z * invd, acc.w * invd};
        v4h oh;
#pragma unroll
        for (int i = 0; i < 4; ++i) {
            float t = y[i] + bias[c + i];
            t = (t - mean[c + i]) * rsqrtf(var[c + i] + EPS_BN) * gamma[c + i] + beta[c + i];
            t = fmaxf(t, 0.f);
            oh[i] = (_Float16)t;
        }
        *(v4h*)(pho + (size_t)n * 256 + c) = oh;
    }
}

// ---- GAT aggregate (1 head) + bias + ReLU + pool-scatter, persistent ----
__device__ void agg1_phase(const _Float16* __restrict__ hin,
                           const float* __restrict__ als, const float* __restrict__ ald,
                           const int* __restrict__ indptr, const int* __restrict__ esrc,
                           const float* __restrict__ bias, const int* __restrict__ batch,
                           float* __restrict__ sums, int bid) {
    const int wv = threadIdx.x >> 6;
    const int lane = threadIdx.x & 63;
    for (int n = bid * 4 + wv; n < N_NODES; n += NB * 4) {
        const int beg = indptr[n], end = indptr[n + 1];
        const float aldn = ald[n];
        float acc = 0.f, sm = 0.f;
        int e = beg;
        for (; e + 7 < end; e += 8) {
            int s[8]; float vv[8]; float hh[8];
#pragma unroll
            for (int j = 0; j < 8; ++j) s[j] = esrc[e + j];
#pragma unroll
            for (int j = 0; j < 8; ++j) {
                vv[j] = als[s[j]] + aldn;
                hh[j] = (float)hin[(size_t)s[j] * 64 + lane];
            }
#pragma unroll
            for (int j = 0; j < 8; ++j) {
                float v = vv[j];
                v = (v > 0.f) ? v : SLOPE * v;
                const float a0 = __expf(v);
                sm += a0;
                acc += a0 * hh[j];
            }
        }
        for (; e < end; ++e) {
            const int s0 = esrc[e];
            float v0 = als[s0] + aldn;
            const float h0 = (float)hin[(size_t)s0 * 64 + lane];
            v0 = (v0 > 0.f) ? v0 : SLOPE * v0;
            const float a0 = __expf(v0);
            sm += a0;
            acc += a0 * h0;
        }
        const float invd = 1.f / (sm + 1e-16f);
        const float val = fmaxf(acc * invd + bias[lane], 0.f);
        atomicAdd(&sums[batch[n] * 64 + lane], val);
    }
}

// ---------------- the megakernel ----------------
__global__ __launch_bounds__(256, 3) void k_mega(MegaArgs a) {
    __shared__ __align__(16) char smraw[17472];   // union: GEMM staging / scan / mlp hid
    const int bid = blockIdx.x;
    const int tid = threadIdx.x;
    _Float16* lbh = (_Float16*)smraw;

    // P0: prep (weight casts, x->fp16, gstart, zero-inits)
    for (int id = bid * 256 + tid; id < PREP_IDS; id += NB * 256) prep_one(id, a);
    gsync(a.ctrl, 0, 0 * 768, NB, bid);

    // P1: CSR build (96 blocks, self-synced) || GEMM1 static 1 tile/block on the rest
    if (bid < CB) {
        csr_build(a, bid, tid, (int*)smraw);
    } else {
        const int t = bid - CB;
        if (t < 626) gemm_tile<4, 512>(a.xh, a.bt1, a.bufH, a.a1s, a.a1d,
                                       a.als1, a.ald1, 4, 256, t >> 1, t & 1, lbh);
    }
    gsync(a.ctrl, 1, 1 * 768, NB, bid);

    // P2: GAT layer-1 aggregate + BN + ReLU -> phf (== xh plane)
    agg4_phase(a.bufH, a.als1, a.ald1, a.indptr, a.esrc,
               a.b1, a.g1, a.be1, a.mu1, a.va1, a.xh, bid);
    gsync(a.ctrl, 2, 2 * 768, NB, bid);

    // P3: GEMM2, static 1 tile/block
    if (bid < 626) gemm_tile<4, 256>(a.xh, a.bt2, a.bufH, a.a2s, a.a2d,
                                     a.als2, a.ald2, 4, 256, bid >> 1, bid & 1, lbh);
    gsync(a.ctrl, 3, 3 * 768, NB, bid);

    // P4: GAT layer-2 aggregate
    agg4_phase(a.bufH, a.als2, a.ald2, a.indptr, a.esrc,
               a.b2, a.g2, a.be2, a.mu2, a.va2, a.xh, bid);
    gsync(a.ctrl, 4, 4 * 768, NB, bid);

    // P5: GEMM3 (64 cols, single head), static 1 tile/block
    if (bid < 313) gemm_tile<2, 256>(a.xh, a.bt3, a.bufH3, a.a3s, a.a3d,
                                     a.als3, a.ald3, 1, 64, bid, 0, lbh);
    gsync(a.ctrl, 5, 5 * 768, NB, bid);

    // P6: GAT layer-3 aggregate + ReLU + pool-scatter
    agg1_phase(a.bufH3, a.als3, a.ald3, a.indptr, a.esrc, a.b3, a.batch, a.sums, bid);
    gsync(a.ctrl, 6, 6 * 768, NB, bid);

    // P7: per-graph MLP head
    if (bid < N_GRAPHS) {
        float* hid = (float*)smraw;
        const int g = bid;
        const int cntn = a.gstart[g + 1] - a.gstart[g];
        const float inv = 1.f / (float)(cntn > 0 ? cntn : 1);
        if (tid < 32) {
            float accv = a.l1b[tid];
            for (int c = 0; c < 64; ++c) accv += (a.sums[g * 64 + c] * inv) * a.l1w[c * 32 + tid];
            hid[tid] = fmaxf(accv, 0.f);
        }
        __syncthreads();
        if (tid < N_CLASSES) {
            float o = a.l2b[tid];
            for (int k = 0; k < 32; ++k) o += hid[k] * a.l2w[k * 5 + tid];
            a.out[g * 5 + tid] = o;
        }
    }
}

extern "C" void kernel_launch(void* const* d_in, const int* in_sizes, int n_in,
                              void* d_out, int out_size, void* d_ws, size_t ws_size,
                              hipStream_t stream) {
    MegaArgs a;
    a.x     = (const float*)d_in[0];
    a.ei    = (const int*)d_in[1];
    a.batch = (const int*)d_in[2];
    a.W1  = (const float*)d_in[3];
    a.a1s = (const float*)d_in[4];
    a.a1d = (const float*)d_in[5];
    a.b1  = (const float*)d_in[6];
    a.g1  = (const float*)d_in[7];
    a.be1 = (const float*)d_in[8];
    a.mu1 = (const float*)d_in[9];
    a.va1 = (const float*)d_in[10];
    a.W2  = (const float*)d_in[11];
    a.a2s = (const float*)d_in[12];
    a.a2d = (const float*)d_in[13];
    a.b2  = (const float*)d_in[14];
    a.g2  = (const float*)d_in[15];
    a.be2 = (const float*)d_in[16];
    a.mu2 = (const float*)d_in[17];
    a.va2 = (const float*)d_in[18];
    a.W3  = (const float*)d_in[19];
    a.a3s = (const float*)d_in[20];
    a.a3d = (const float*)d_in[21];
    a.b3  = (const float*)d_in[22];
    a.l1w = (const float*)d_in[23];
    a.l1b = (const float*)d_in[24];
    a.l2w = (const float*)d_in[25];
    a.l2b = (const float*)d_in[26];
    a.out = (float*)d_out;

    char* w = (char*)d_ws;
    size_t off = 0;
    auto alloc = [&](size_t bytes) -> void* {
        void* p = w + off;
        off += (bytes + 255) & ~(size_t)255;
        return p;
    };
    a.xh    = (_Float16*)alloc((size_t)N_NODES * 512 * 2);   // layer-1 A; reused as phf plane
    a.bufH  = (_Float16*)alloc((size_t)N_NODES * 256 * 2);
    a.bufH3 = (_Float16*)alloc((size_t)N_NODES * 64 * 2);
    a.bt1 = (_Float16*)alloc((size_t)512 * 256 * 2);
    a.bt2 = (_Float16*)alloc((size_t)256 * 256 * 2);
    a.bt3 = (_Float16*)alloc((size_t)256 * 64 * 2);
    a.albase = (float*)alloc((size_t)ALZ * 4);
    a.als1 = a.albase;
    a.ald1 = a.albase + 80000;
    a.als2 = a.albase + 160000;
    a.ald2 = a.albase + 240000;
    a.als3 = a.albase + 320000;
    a.ald3 = a.albase + 340000;
    a.cnt    = (int*)alloc((size_t)N_NODES * 4);
    a.wptr   = (int*)alloc((size_t)N_NODES * 4);
    a.indptr = (int*)alloc((size_t)(N_NODES + 1) * 4);
    a.esrc   = (int*)alloc((size_t)E_TOT * 4);
    a.gstart = (int*)alloc((size_t)(N_GRAPHS + 1) * 4);
    a.sums   = (float*)alloc((size_t)N_GRAPHS * 64 * 4);
    a.blocksum = (int*)alloc((size_t)CB * 4);
    a.ctrl     = (int*)alloc((size_t)CTRL_INTS * 4);

    // barrier cells + release words must be zero at every graph replay
    hipMemsetAsync(a.ctrl, 0, (size_t)CTRL_INTS * 4, stream);
    k_mega<<<NB, 256, 0, stream>>>(a);
}